// Round 7
// baseline (747.865 us; speedup 1.0000x reference)
//
#include <hip/hip_runtime.h>
#include <stdint.h>

#define NN 65536
#define BB 64
#define TPB 256
#define BPB 16                    // blocks per batch
#define GRID (BB * BPB)           // 1024 blocks == 4/CU * 256 CU (co-resident)
#define PPT 16                    // points per thread
#define PPBK 4096                 // points per block

// Exact-fp32 squared distance, matching numpy's ((dx*dx + dy*dy) + dz*dz)
// with no FMA contraction (rn intrinsics are never fused).
__device__ __forceinline__ float sqdist(float x, float y, float z,
                                        float cx, float cy, float cz) {
    float dx = __fsub_rn(x, cx);
    float dy = __fsub_rn(y, cy);
    float dz = __fsub_rn(z, cz);
    return __fadd_rn(__fadd_rn(__fmul_rn(dx, dx), __fmul_rn(dy, dy)),
                     __fmul_rn(dz, dz));
}

// Packed argmax key: (fp32 bits << 32) | (0xFFFFFFFF - index).
// Distances >= 0 so fp32 bit order == value order; ~index makes u64-max
// prefer the SMALLEST index on value ties (np.argmax semantics).
// Key is never 0 (idx <= 65535 -> low word >= 0xFFFF0000), so 0 = "not ready".
__device__ __forceinline__ unsigned long long pack_key(float v, int i) {
    return ((unsigned long long)__float_as_uint(v) << 32) |
           (unsigned long long)(0xFFFFFFFFu - (unsigned)i);
}
__device__ __forceinline__ int key_idx(unsigned long long key) {
    return (int)(0xFFFFFFFFu - (unsigned)(key & 0xFFFFFFFFu));
}

// Single fused kernel: 4 FPS iterations (xyz + min_d in registers), keep-mask,
// stable compaction, cyclic gather. Sync is PER-BATCH (16 blocks) via
// agent-scope atomics on zeroed flags; __launch_bounds__(256,4) guarantees
// 4 blocks/CU -> all 1024 blocks co-resident -> spins cannot deadlock.
__global__ __launch_bounds__(TPB, 4) void fused_kernel(
        const float* __restrict__ pts,
        unsigned long long* flag,      // [3][BB], zeroed
        int* cnt,                      // [4][BB], zeroed
        unsigned long long* partKey,   // [3][GRID]
        unsigned long long* masks,     // [BB][1024]
        float* __restrict__ out) {
    const int gb = blockIdx.x;
    const int b = gb >> 4, blk = gb & 15;
    const int tid = threadIdx.x;
    const int lane = tid & 63, wid = tid >> 6;
    const float* base = pts + (size_t)b * NN * 6;

    // ---- load owned xyz into registers ----
    float x[PPT], y[PPT], z[PPT], mind[PPT];
    #pragma unroll
    for (int l = 0; l < PPT; ++l) {
        const int p = blk * PPBK + l * TPB + tid;   // coalesced across lanes
        const float* q = base + (size_t)p * 6;
        float2 xy = *(const float2*)q;              // 24B stride, 8B aligned
        x[l] = xy.x; y[l] = xy.y; z[l] = q[2];
        mind[l] = 1e10f;                            // matches jnp init
    }
    float cx = base[0], cy = base[1], cz = base[2]; // center 0 = point 0

    __shared__ unsigned long long s_k[4];
    __shared__ float s_ctr[3];

    // ---- FPS: 4 min-updates, 3 per-batch argmaxes ----
    for (int ph = 0; ph < 4; ++ph) {
        float bestv = -1.0f; int besti = 0;
        #pragma unroll
        for (int l = 0; l < PPT; ++l) {
            float d = sqdist(x[l], y[l], z[l], cx, cy, cz);
            float m = fminf(mind[l], d);
            mind[l] = m;
            if (m > bestv) { bestv = m; besti = blk * PPBK + l * TPB + tid; }
        }
        if (ph == 3) break;                         // last update: no argmax

        unsigned long long key = pack_key(bestv, besti);
        #pragma unroll
        for (int off = 32; off > 0; off >>= 1) {
            unsigned long long ok = __shfl_down(key, off, 64);
            if (ok > key) key = ok;
        }
        if (lane == 0) s_k[wid] = key;
        __syncthreads();
        if (tid == 0) {
            unsigned long long bk = s_k[0];
            #pragma unroll
            for (int w = 1; w < 4; ++w) bk = (s_k[w] > bk) ? s_k[w] : bk;
            __hip_atomic_store(&partKey[ph * GRID + gb], bk,
                               __ATOMIC_RELEASE, __HIP_MEMORY_SCOPE_AGENT);
            int prev = atomicAdd(&cnt[ph * BB + b], 1);
            unsigned long long win;
            if (prev == BPB - 1) {                  // last arriver reduces
                const unsigned long long* s = partKey + ph * GRID + b * BPB;
                win = __hip_atomic_load(&s[0], __ATOMIC_ACQUIRE,
                                        __HIP_MEMORY_SCOPE_AGENT);
                #pragma unroll
                for (int w = 1; w < BPB; ++w) {
                    unsigned long long v = __hip_atomic_load(
                        &s[w], __ATOMIC_ACQUIRE, __HIP_MEMORY_SCOPE_AGENT);
                    if (v > win) win = v;
                }
                __hip_atomic_store(&flag[ph * BB + b], win,
                                   __ATOMIC_RELEASE, __HIP_MEMORY_SCOPE_AGENT);
            } else {                                // spin on published winner
                do {
                    win = __hip_atomic_load(&flag[ph * BB + b],
                                            __ATOMIC_ACQUIRE,
                                            __HIP_MEMORY_SCOPE_AGENT);
                    if (!win) __builtin_amdgcn_s_sleep(8);
                } while (!win);
            }
            const float* c = base + (size_t)key_idx(win) * 6;
            s_ctr[0] = c[0]; s_ctr[1] = c[1]; s_ctr[2] = c[2];
        }
        __syncthreads();
        cx = s_ctr[0]; cy = s_ctr[1]; cz = s_ctr[2];
    }

    // ---- keep mask (sqrt_rn monotone+exact: sqrt(min d^2)==min(norm)) ----
    unsigned long long* mb = masks + (size_t)b * 1024;
    #pragma unroll
    for (int l = 0; l < PPT; ++l) {
        int keep = (__fsqrt_rn(mind[l]) >= 0.2f) ? 1 : 0;
        unsigned long long m = __ballot(keep);      // bit L == point base+L
        if (lane == 0)
            __hip_atomic_store(&mb[blk * 64 + l * 4 + wid], m,
                               __ATOMIC_RELAXED, __HIP_MEMORY_SCOPE_AGENT);
    }
    __threadfence();                                // each thread: release own stores
    __syncthreads();
    if (tid == 0) {
        atomicAdd(&cnt[3 * BB + b], 1);
        int c;
        do {
            c = __hip_atomic_load(&cnt[3 * BB + b], __ATOMIC_ACQUIRE,
                                  __HIP_MEMORY_SCOPE_AGENT);
            if (c < BPB) __builtin_amdgcn_s_sleep(8);
        } while (c < BPB);
    }
    __syncthreads();                                // whole batch's masks ready

    // ---- compaction prefix in LDS (agent loads: cross-XCD coherent) ----
    __shared__ uint64_t s_m[1024];
    __shared__ int s_pre[1024];
    __shared__ int s_ws[4], s_wo[4];
    __shared__ int s_nvs;
    uint64_t w[4];
    int cnt4 = 0;
    #pragma unroll
    for (int k = 0; k < 4; ++k) {
        w[k] = __hip_atomic_load(&mb[tid * 4 + k], __ATOMIC_RELAXED,
                                 __HIP_MEMORY_SCOPE_AGENT);
        s_m[tid * 4 + k] = w[k];
        cnt4 += __popcll(w[k]);
    }
    int incl = cnt4;
    #pragma unroll
    for (int off = 1; off < 64; off <<= 1) {
        int v = __shfl_up(incl, off, 64);
        if (lane >= off) incl += v;
    }
    if (lane == 63) s_ws[wid] = incl;
    __syncthreads();
    if (tid == 0) {
        int run = 0;
        #pragma unroll
        for (int q = 0; q < 4; ++q) { s_wo[q] = run; run += s_ws[q]; }
        s_nvs = run;
    }
    __syncthreads();
    int run = s_wo[wid] + incl - cnt4;              // exclusive prefix, word 4t
    #pragma unroll
    for (int k = 0; k < 4; ++k) {
        s_pre[tid * 4 + k] = run;
        run += __popcll(w[k]);
    }
    __syncthreads();

    // ---- cyclic gather: this block writes rows [blk*4096, blk*4096+4096) ----
    const int nv = s_nvs;
    float* ob = out + (size_t)b * NN * 6;
    if (nv <= 0) {
        float2 zz = make_float2(0.f, 0.f);
        #pragma unroll
        for (int l = 0; l < PPT; ++l) {
            int j = blk * PPBK + l * TPB + tid;
            float2* o = (float2*)(ob + (size_t)j * 6);
            o[0] = zz; o[1] = zz; o[2] = zz;
        }
        return;
    }
    #pragma unroll
    for (int l = 0; l < PPT; ++l) {
        int j = blk * PPBK + l * TPB + tid;         // coalesced across lanes
        int jj = (int)((unsigned)j % (unsigned)nv); // rank of source point
        // largest word wd with s_pre[wd] <= jj (s_pre[0]==0 always <= jj)
        int wd = 0;
        #pragma unroll
        for (int s = 512; s > 0; s >>= 1) {
            int cand = wd + s;
            if (cand < 1024 && s_pre[cand] <= jj) wd = cand;
        }
        int r = jj - s_pre[wd];
        uint64_t m = s_m[wd];
        int bit = 0, c;
        c = __popcll(m & 0xFFFFFFFFull);
        if (r >= c) { r -= c; m >>= 32; bit += 32; }
        c = __popcll(m & 0xFFFFull);
        if (r >= c) { r -= c; m >>= 16; bit += 16; }
        c = __popcll(m & 0xFFull);
        if (r >= c) { r -= c; m >>= 8; bit += 8; }
        c = __popcll(m & 0xFull);
        if (r >= c) { r -= c; m >>= 4; bit += 4; }
        c = __popcll(m & 0x3ull);
        if (r >= c) { r -= c; m >>= 2; bit += 2; }
        if (r >= (int)(m & 1ull)) { bit += 1; }
        int src = wd * 64 + bit;
        const float2* p = (const float2*)(base + (size_t)src * 6);
        float2* o = (float2*)(ob + (size_t)j * 6);
        float2 r0 = p[0], r1 = p[1], r2 = p[2];
        o[0] = r0; o[1] = r1; o[2] = r2;
    }
}

extern "C" void kernel_launch(void* const* d_in, const int* in_sizes, int n_in,
                              void* d_out, int out_size, void* d_ws, size_t ws_size,
                              hipStream_t stream) {
    const float* pts = (const float*)d_in[0];
    float* out = (float*)d_out;

    // ws layout: [flag 3*64 u64 | pad | cnt 4*64 int]  <- zeroed (4 KB memset)
    //            [partKey 3*GRID u64 @4K] [masks 64*1024 u64 @64K]
    unsigned long long* flag    = (unsigned long long*)d_ws;
    int*                cnt     = (int*)((char*)d_ws + 2048);
    unsigned long long* partKey = (unsigned long long*)((char*)d_ws + 4096);
    unsigned long long* masks   = (unsigned long long*)((char*)d_ws + (64 << 10));

    hipMemsetAsync(d_ws, 0, 4096, stream);
    fused_kernel<<<GRID, TPB, 0, stream>>>(pts, flag, cnt, partKey, masks, out);
}